// Round 9
// baseline (121.360 us; speedup 1.0000x reference)
//
#include <hip/hip_runtime.h>
#include <math.h>

// MutualInformationLoss on MI355X — round 9.
// Round-8: 42 us harness ws-poison fill (fixed floor) + K1 ~43 + tail ~23.
// Changes:
//  (a) K1 image columns XOR-swizzled: col' = col ^ (8*(row&7)). Scatter bank
//      was (4*row + lane/2)%32 — row-correlated collisions; swizzle breaks
//      them. b128 fragment reads stay 16B-aligned (col groups of 8 preserved).
//  (b) Tail: K1 p==0 blocks zero pab64+flag; K2 = reduce + last-block
//      finalize (threadfence + ticket, agent-scope atomic loads). Drops the
//      memset dispatch and mi_final dispatch.

#define NBINS   23
#define NCELLS  529
#define NBATCH  4
#define NVOX    884736
#define PBLK    432               // K1 blocks per batch: 432 * 2048 = 884736
#define RPB     16                // partial rows per reduce block (432/27)
#define RBLK    (PBLK / RPB)      // 27
#define RS      72                // image row stride in halves (144 B)
#define IMGB    (32 * RS * 2)     // 4608 B per image (32 rows)
#define WREG    (2 * IMGB)        // 9216 B per wave (A + B images)

#define SWZ(r, c) ((c) ^ (((r) & 7) << 3))   // bank-decorrelating col swizzle

typedef float    vf4  __attribute__((ext_vector_type(4)));
typedef _Float16 h8   __attribute__((ext_vector_type(8)));
typedef float    f16v __attribute__((ext_vector_type(16)));

#define G1 0.13533528f        // exp(-2)
#define G2 3.3546263e-4f      // exp(-8)
#define G3 1.5229979e-8f      // exp(-18)

// 7-bin window at rows i0..i0+6 via factored Gaussian (2 exp + 1 rcp):
//   w(t) = W0 * R^t * G(t), W0=exp(-968 v^2), R=exp(88 v), v = x - c_mid
__device__ __forceinline__ float window7(float x, int& i0, float* w)
{
    x = fminf(fmaxf(x, 0.0f), 1.0f);
    int ka = (int)floorf(fmaf(x, 22.0f, 0.5f));
    i0 = min(max(ka - 3, 0), 16);
    float v  = fmaf((float)(i0 + 3), -(1.0f / 22.0f), x);
    float W0 = __expf(-968.0f * v * v);
    float R  = __expf(88.0f * v);
    float Ri = __builtin_amdgcn_rcpf(R);
    float R2 = R * R,   R3 = R2 * R;
    float R2i = Ri * Ri, R3i = R2i * Ri;
    w[0] = W0 * (R3i * G3);
    w[1] = W0 * (R2i * G2);
    w[2] = W0 * (Ri  * G1);
    w[3] = W0;
    w[4] = W0 * (R   * G1);
    w[5] = W0 * (R2  * G2);
    w[6] = W0 * (R3  * G3);
    return ((w[0] + w[6]) + (w[1] + w[5])) + ((w[2] + w[4]) + w[3]);
}

// ---------------- K1: fused Parzen-window + MFMA joint histogram ----------------
__global__ __launch_bounds__(256)
void mi_mfma(const float* __restrict__ pred,
             const float* __restrict__ targ,
             float* __restrict__ partial,      // [NBATCH*PBLK][NCELLS]
             double* __restrict__ pab64,       // zeroed here (stream-ordered)
             unsigned int* __restrict__ flag)
{
    __shared__ __align__(16) char smem[4 * WREG];   // 36864 B -> 4 blocks/CU

    const int p    = blockIdx.x;
    const int b    = blockIdx.y;
    const int wv   = threadIdx.x >> 6;
    const int lane = threadIdx.x & 63;
    const int m    = lane & 31;               // bin row for fragment reads
    const int h    = lane >> 5;               // k-half selector

    // init duty: zero pab64 + ticket flag (K2 runs strictly after K1)
    if (p == 0) {
        for (int c = threadIdx.x; c < NCELLS; c += 256)
            pab64[b * NCELLS + c] = 0.0;
        if (b == 0 && threadIdx.x == 0) *flag = 0u;
    }

    char* wbase = smem + wv * WREG;
    _Float16* Aimg = (_Float16*)wbase;
    _Float16* Bimg = (_Float16*)(wbase + IMGB);

    const size_t base = (size_t)b * NVOX + (size_t)p * 2048 + (size_t)wv * 512
                      + (size_t)lane * 8;
    const vf4* __restrict__ px4 = (const vf4*)(pred + base);
    const vf4* __restrict__ py4 = (const vf4*)(targ + base);
    vf4 xa = px4[0], xb = px4[1], ya = py4[0], yb = py4[1];
    float xs[8] = {xa.x, xa.y, xa.z, xa.w, xb.x, xb.y, xb.z, xb.w};
    float ys[8] = {ya.x, ya.y, ya.z, ya.w, yb.x, yb.y, yb.z, yb.w};

    f16v acc = {};

    #pragma unroll
    for (int c = 0; c < 8; ++c) {
        // zero rows 0..23 of both images; rows 24..31 stay garbage — they
        // only pollute C rows/cols >= 23, which are never read
        vf4 z = {0.f, 0.f, 0.f, 0.f};
        #pragma unroll
        for (int it = 0; it < 3; ++it) {
            *(vf4*)(wbase        + (it * 64 + lane) * 16) = z;
            *(vf4*)(wbase + IMGB + (it * 64 + lane) * 16) = z;
        }
        if (lane < 24) {
            *(vf4*)(wbase        + (192 + lane) * 16) = z;
            *(vf4*)(wbase + IMGB + (192 + lane) * 16) = z;
        }

        int ia, ja;
        float wa[7], wb[7];
        float sa = window7(xs[c], ia, wa);
        float sb = window7(ys[c], ja, wb);
        float inv = __builtin_amdgcn_rcpf(sa * sb);   // fold both norms onto A

        #pragma unroll
        for (int t = 0; t < 7; ++t) {
            int ra = ia + t, rb = ja + t;
            Aimg[ra * RS + SWZ(ra, lane)] = (_Float16)(wa[t] * inv);  // RNE cvt
            Bimg[rb * RS + SWZ(rb, lane)] = (_Float16)wb[t];
        }

        // 4 k-steps of 32x32x16; fragment cols are 8-aligned groups, so the
        // swizzle keeps each read one 16B-aligned b128
        #pragma unroll
        for (int s = 0; s < 4; ++s) {
            h8 Af = *(const h8*)(Aimg + m * RS + SWZ(m, 16 * s + 8 * h));
            h8 Bf = *(const h8*)(Bimg + m * RS + SWZ(m, 16 * s + 8 * h));
            acc = __builtin_amdgcn_mfma_f32_32x32x16_f16(Af, Bf, acc, 0, 0, 0);
        }
    }

    // epilogue: C layout col=lane&31, row=(reg&3)+8*(reg>>2)+4*h (m74/m101)
    float* tile = (float*)wbase;               // reuse wave region
    #pragma unroll
    for (int r = 0; r < 16; ++r) {
        int row = (r & 3) + 8 * (r >> 2) + 4 * h;
        tile[row * 33 + m] = acc[r];
    }
    __syncthreads();
    for (int c = threadIdx.x; c < NCELLS; c += 256) {
        int i = c / NBINS, j = c % NBINS;
        float s = 0.0f;
        #pragma unroll
        for (int w = 0; w < 4; ++w)
            s += ((const float*)(smem + w * WREG))[i * 33 + j];
        partial[((size_t)(b * PBLK + p)) * NCELLS + c] = s;   // coalesced rows
    }
}

// ---- K2: coalesced+parallel fp64 reduction, last block finalizes MI ----
__global__ __launch_bounds__(256)
void mi_reduce_final(const float* __restrict__ partial,
                     double* __restrict__ pab64,
                     unsigned int* __restrict__ flag,
                     float* __restrict__ out)
{
    const int g = blockIdx.x;                 // 0..RBLK-1
    const int b = blockIdx.y;
    const int t = threadIdx.x;
    const float* __restrict__ src =
        partial + ((size_t)b * PBLK + (size_t)g * RPB) * NCELLS;

    double a0 = 0.0, a1 = 0.0, a2 = 0.0;
    #pragma unroll
    for (int p = 0; p < RPB; ++p) {
        const float* __restrict__ row = src + (size_t)p * NCELLS;
        a0 += (double)row[t];
        a1 += (double)row[256 + t];
        if (t < NCELLS - 512) a2 += (double)row[512 + t];
    }
    atomicAdd(&pab64[b * NCELLS + t],       a0);
    atomicAdd(&pab64[b * NCELLS + 256 + t], a1);
    if (t < NCELLS - 512) atomicAdd(&pab64[b * NCELLS + 512 + t], a2);

    // ticket: last of the 108 blocks finalizes
    __threadfence();
    __shared__ int is_last;
    if (t == 0)
        is_last = (atomicAdd(flag, 1u) == (unsigned)(RBLK * NBATCH - 1));
    __syncthreads();
    if (!is_last) return;
    __threadfence();

    __shared__ double s_pab[NCELLS];
    __shared__ double s_pa[NBINS];
    __shared__ double s_pb[NBINS];
    __shared__ double s_red[4];

    double total = 0.0;
    for (int bb = 0; bb < NBATCH; ++bb) {
        for (int c = t; c < NCELLS; c += 256) {
            // agent-scope atomic load: bypasses possibly-stale local caches
            double v = __hip_atomic_load(&pab64[bb * NCELLS + c],
                                         __ATOMIC_RELAXED,
                                         __HIP_MEMORY_SCOPE_AGENT);
            s_pab[c] = v * (1.0 / (double)NVOX);
        }
        __syncthreads();
        if (t < NBINS) {
            double r = 0.0, cl = 0.0;
            for (int j = 0; j < NBINS; ++j) {
                r  += s_pab[t * NBINS + j];
                cl += s_pab[j * NBINS + t];
            }
            s_pa[t] = r; s_pb[t] = cl;
        }
        __syncthreads();
        double s = 0.0;
        for (int c = t; c < NCELLS; c += 256) {
            double pv   = s_pab[c];
            double papb = s_pa[c / NBINS] * s_pb[c % NBINS];
            s += pv * log((pv + 1e-7) / (papb + 1e-7) + 1e-7);
        }
        #pragma unroll
        for (int off = 32; off > 0; off >>= 1) s += __shfl_down(s, off, 64);
        if ((t & 63) == 0) s_red[t >> 6] = s;
        __syncthreads();
        if (t == 0) total += s_red[0] + s_red[1] + s_red[2] + s_red[3];
        __syncthreads();
    }
    if (t == 0) out[0] = (float)(-total * 0.25);
}

extern "C" void kernel_launch(void* const* d_in, const int* in_sizes, int n_in,
                              void* d_out, int out_size, void* d_ws, size_t ws_size,
                              hipStream_t stream)
{
    const float* pred = (const float*)d_in[0];
    const float* targ = (const float*)d_in[1];
    float* out = (float*)d_out;
    char* ws = (char*)d_ws;

    // layout: [partial: 3.66 MB][pab64: 2116 f64][flag: u32]
    const size_t off_partial = 0;
    const size_t off_pab64   =
        ((size_t)NBATCH * PBLK * NCELLS * 4 + 255) & ~(size_t)255;
    const size_t off_flag    = off_pab64 + (size_t)NBATCH * NCELLS * 8;

    float*        partial = (float*)(ws + off_partial);
    double*       pab64   = (double*)(ws + off_pab64);
    unsigned int* flag    = (unsigned int*)(ws + off_flag);

    mi_mfma<<<dim3(PBLK, NBATCH), 256, 0, stream>>>(pred, targ, partial,
                                                    pab64, flag);
    mi_reduce_final<<<dim3(RBLK, NBATCH), 256, 0, stream>>>(partial, pab64,
                                                            flag, out);
}

// Round 10
// 112.938 us; speedup vs baseline: 1.0746x; 1.0746x over previous
//
#include <hip/hip_runtime.h>
#include <math.h>

// MutualInformationLoss on MI355X — round 10.
// r9 post-mortem: XOR col-swizzle fixed scatter-WRITE banks but broke the
// b128 fragment READ banks (g=(2s+h)^(m&7) makes m+g non-bijective mod 8 ->
// 4-way pileups on the big 1024B reads, +13 us — the whole regression).
// r10 = r8's conflict-free addressing + r9's fused tail (ticket finalize,
// 2 dispatches total). Data-dependent scatter rows can't be bank-fixed by
// any col swizzle that preserves 16B read groups — leave writes as-is.

#define NBINS   23
#define NCELLS  529
#define NBATCH  4
#define NVOX    884736
#define PBLK    432               // K1 blocks per batch: 432 * 2048 = 884736
#define RPB     16                // partial rows per reduce block (432/27)
#define RBLK    (PBLK / RPB)      // 27
#define RS      72                // image row stride in halves (144 B)
#define IMGB    (32 * RS * 2)     // 4608 B per image (32 rows)
#define WREG    (2 * IMGB)        // 9216 B per wave (A + B images)

typedef float    vf4  __attribute__((ext_vector_type(4)));
typedef _Float16 h8   __attribute__((ext_vector_type(8)));
typedef float    f16v __attribute__((ext_vector_type(16)));

#define G1 0.13533528f        // exp(-2)
#define G2 3.3546263e-4f      // exp(-8)
#define G3 1.5229979e-8f      // exp(-18)

// 7-bin window at rows i0..i0+6 via factored Gaussian (2 exp + 1 rcp):
//   w(t) = W0 * R^t * G(t), W0=exp(-968 v^2), R=exp(88 v), v = x - c_mid
__device__ __forceinline__ float window7(float x, int& i0, float* w)
{
    x = fminf(fmaxf(x, 0.0f), 1.0f);
    int ka = (int)floorf(fmaf(x, 22.0f, 0.5f));
    i0 = min(max(ka - 3, 0), 16);
    float v  = fmaf((float)(i0 + 3), -(1.0f / 22.0f), x);
    float W0 = __expf(-968.0f * v * v);
    float R  = __expf(88.0f * v);
    float Ri = __builtin_amdgcn_rcpf(R);
    float R2 = R * R,   R3 = R2 * R;
    float R2i = Ri * Ri, R3i = R2i * Ri;
    w[0] = W0 * (R3i * G3);
    w[1] = W0 * (R2i * G2);
    w[2] = W0 * (Ri  * G1);
    w[3] = W0;
    w[4] = W0 * (R   * G1);
    w[5] = W0 * (R2  * G2);
    w[6] = W0 * (R3  * G3);
    return ((w[0] + w[6]) + (w[1] + w[5])) + ((w[2] + w[4]) + w[3]);
}

// ---------------- K1: fused Parzen-window + MFMA joint histogram ----------------
__global__ __launch_bounds__(256)
void mi_mfma(const float* __restrict__ pred,
             const float* __restrict__ targ,
             float* __restrict__ partial,      // [NBATCH*PBLK][NCELLS]
             double* __restrict__ pab64,       // zeroed here (stream-ordered)
             unsigned int* __restrict__ flag)
{
    __shared__ __align__(16) char smem[4 * WREG];   // 36864 B -> 4 blocks/CU

    const int p    = blockIdx.x;
    const int b    = blockIdx.y;
    const int wv   = threadIdx.x >> 6;
    const int lane = threadIdx.x & 63;
    const int m    = lane & 31;               // bin row for fragment reads
    const int h    = lane >> 5;               // k-half selector

    // init duty: zero pab64 + ticket flag (K2 runs strictly after K1)
    if (p == 0) {
        for (int c = threadIdx.x; c < NCELLS; c += 256)
            pab64[b * NCELLS + c] = 0.0;
        if (b == 0 && threadIdx.x == 0) *flag = 0u;
    }

    char* wbase = smem + wv * WREG;
    _Float16* Aimg = (_Float16*)wbase;
    _Float16* Bimg = (_Float16*)(wbase + IMGB);

    const size_t base = (size_t)b * NVOX + (size_t)p * 2048 + (size_t)wv * 512
                      + (size_t)lane * 8;
    const vf4* __restrict__ px4 = (const vf4*)(pred + base);
    const vf4* __restrict__ py4 = (const vf4*)(targ + base);
    vf4 xa = px4[0], xb = px4[1], ya = py4[0], yb = py4[1];
    float xs[8] = {xa.x, xa.y, xa.z, xa.w, xb.x, xb.y, xb.z, xb.w};
    float ys[8] = {ya.x, ya.y, ya.z, ya.w, yb.x, yb.y, yb.z, yb.w};

    f16v acc = {};

    #pragma unroll
    for (int c = 0; c < 8; ++c) {
        // zero rows 0..23 of both images; rows 24..31 stay garbage — they
        // only pollute C rows/cols >= 23, which are never read
        vf4 z = {0.f, 0.f, 0.f, 0.f};
        #pragma unroll
        for (int it = 0; it < 3; ++it) {
            *(vf4*)(wbase        + (it * 64 + lane) * 16) = z;
            *(vf4*)(wbase + IMGB + (it * 64 + lane) * 16) = z;
        }
        if (lane < 24) {
            *(vf4*)(wbase        + (192 + lane) * 16) = z;
            *(vf4*)(wbase + IMGB + (192 + lane) * 16) = z;
        }

        int ia, ja;
        float wa[7], wb[7];
        float sa = window7(xs[c], ia, wa);
        float sb = window7(ys[c], ja, wb);
        float inv = __builtin_amdgcn_rcpf(sa * sb);   // fold both norms onto A

        #pragma unroll
        for (int t = 0; t < 7; ++t) {
            Aimg[(ia + t) * RS + lane] = (_Float16)(wa[t] * inv);  // RNE cvt
            Bimg[(ja + t) * RS + lane] = (_Float16)wb[t];
        }

        // 4 k-steps of 32x32x16 (K=16 voxels each); reads are bank-balanced:
        // bank base 4(m)+4h+8s -> 8 lanes per 4-bank group, zero conflicts
        #pragma unroll
        for (int s = 0; s < 4; ++s) {
            h8 Af = *(const h8*)(Aimg + m * RS + 16 * s + 8 * h);
            h8 Bf = *(const h8*)(Bimg + m * RS + 16 * s + 8 * h);
            acc = __builtin_amdgcn_mfma_f32_32x32x16_f16(Af, Bf, acc, 0, 0, 0);
        }
    }

    // epilogue: C layout col=lane&31, row=(reg&3)+8*(reg>>2)+4*h (m74/m101)
    float* tile = (float*)wbase;               // reuse wave region
    #pragma unroll
    for (int r = 0; r < 16; ++r) {
        int row = (r & 3) + 8 * (r >> 2) + 4 * h;
        tile[row * 33 + m] = acc[r];
    }
    __syncthreads();
    for (int c = threadIdx.x; c < NCELLS; c += 256) {
        int i = c / NBINS, j = c % NBINS;
        float s = 0.0f;
        #pragma unroll
        for (int w = 0; w < 4; ++w)
            s += ((const float*)(smem + w * WREG))[i * 33 + j];
        partial[((size_t)(b * PBLK + p)) * NCELLS + c] = s;   // coalesced rows
    }
}

// ---- K2: coalesced+parallel fp64 reduction, last block finalizes MI ----
__global__ __launch_bounds__(256)
void mi_reduce_final(const float* __restrict__ partial,
                     double* __restrict__ pab64,
                     unsigned int* __restrict__ flag,
                     float* __restrict__ out)
{
    const int g = blockIdx.x;                 // 0..RBLK-1
    const int b = blockIdx.y;
    const int t = threadIdx.x;
    const float* __restrict__ src =
        partial + ((size_t)b * PBLK + (size_t)g * RPB) * NCELLS;

    double a0 = 0.0, a1 = 0.0, a2 = 0.0;
    #pragma unroll
    for (int p = 0; p < RPB; ++p) {
        const float* __restrict__ row = src + (size_t)p * NCELLS;
        a0 += (double)row[t];
        a1 += (double)row[256 + t];
        if (t < NCELLS - 512) a2 += (double)row[512 + t];
    }
    atomicAdd(&pab64[b * NCELLS + t],       a0);
    atomicAdd(&pab64[b * NCELLS + 256 + t], a1);
    if (t < NCELLS - 512) atomicAdd(&pab64[b * NCELLS + 512 + t], a2);

    // ticket: last of the 108 blocks finalizes
    __threadfence();
    __shared__ int is_last;
    if (t == 0)
        is_last = (atomicAdd(flag, 1u) == (unsigned)(RBLK * NBATCH - 1));
    __syncthreads();
    if (!is_last) return;
    __threadfence();

    __shared__ double s_pab[NCELLS];
    __shared__ double s_pa[NBINS];
    __shared__ double s_pb[NBINS];
    __shared__ double s_red[4];

    double total = 0.0;
    for (int bb = 0; bb < NBATCH; ++bb) {
        for (int c = t; c < NCELLS; c += 256) {
            // agent-scope atomic load: bypasses possibly-stale local caches
            double v = __hip_atomic_load(&pab64[bb * NCELLS + c],
                                         __ATOMIC_RELAXED,
                                         __HIP_MEMORY_SCOPE_AGENT);
            s_pab[c] = v * (1.0 / (double)NVOX);
        }
        __syncthreads();
        if (t < NBINS) {
            double r = 0.0, cl = 0.0;
            for (int j = 0; j < NBINS; ++j) {
                r  += s_pab[t * NBINS + j];
                cl += s_pab[j * NBINS + t];
            }
            s_pa[t] = r; s_pb[t] = cl;
        }
        __syncthreads();
        double s = 0.0;
        for (int c = t; c < NCELLS; c += 256) {
            double pv   = s_pab[c];
            double papb = s_pa[c / NBINS] * s_pb[c % NBINS];
            s += pv * log((pv + 1e-7) / (papb + 1e-7) + 1e-7);
        }
        #pragma unroll
        for (int off = 32; off > 0; off >>= 1) s += __shfl_down(s, off, 64);
        if ((t & 63) == 0) s_red[t >> 6] = s;
        __syncthreads();
        if (t == 0) total += s_red[0] + s_red[1] + s_red[2] + s_red[3];
        __syncthreads();
    }
    if (t == 0) out[0] = (float)(-total * 0.25);
}

extern "C" void kernel_launch(void* const* d_in, const int* in_sizes, int n_in,
                              void* d_out, int out_size, void* d_ws, size_t ws_size,
                              hipStream_t stream)
{
    const float* pred = (const float*)d_in[0];
    const float* targ = (const float*)d_in[1];
    float* out = (float*)d_out;
    char* ws = (char*)d_ws;

    // layout: [partial: 3.66 MB][pab64: 2116 f64][flag: u32]
    const size_t off_partial = 0;
    const size_t off_pab64   =
        ((size_t)NBATCH * PBLK * NCELLS * 4 + 255) & ~(size_t)255;
    const size_t off_flag    = off_pab64 + (size_t)NBATCH * NCELLS * 8;

    float*        partial = (float*)(ws + off_partial);
    double*       pab64   = (double*)(ws + off_pab64);
    unsigned int* flag    = (unsigned int*)(ws + off_flag);

    mi_mfma<<<dim3(PBLK, NBATCH), 256, 0, stream>>>(pred, targ, partial,
                                                    pab64, flag);
    mi_reduce_final<<<dim3(RBLK, NBATCH), 256, 0, stream>>>(partial, pab64,
                                                            flag, out);
}

// Round 11
// 111.677 us; speedup vs baseline: 1.0867x; 1.0113x over previous
//
#include <hip/hip_runtime.h>
#include <math.h>

// MutualInformationLoss on MI355X — round 11.
// K1 was stall-bound (~40 us vs 24 us LDS-pipe floor) at 16 waves/CU.
// Change: 23-row LDS images (reads for m>=23 clamp to row 22 — those C
// rows/cols are discarded, result bit-identical). Block LDS 36.9->26.5 KB
// => 6 blocks/CU = 24 waves/CU; grid 1536 = exactly 6 x 256 CUs (single
// residency round). Per-chunk coalesced dword voxel loads (9 chunks/wave).
// Tail = r8's measured-best: 17 KB memset + reduce(24x4) + final(1).

#define NBINS   23
#define NCELLS  529
#define NBATCH  4
#define NVOX    884736
#define PBLK    384               // blocks per batch: 384 * 2304 = 884736
#define VPB     2304              // voxels per block
#define VPW     576               // voxels per wave (9 chunks of 64)
#define NCHUNK  9
#define RPB     16                // partial rows per reduce block
#define RBLK    (PBLK / RPB)      // 24
#define RS      72                // image row stride in halves (144 B)
#define IMGB    (23 * RS * 2)     // 3312 B per image (23 rows, 16B-multiple)
#define WREG    (2 * IMGB)        // 6624 B per wave (A + B images)

typedef float    vf4  __attribute__((ext_vector_type(4)));
typedef _Float16 h8   __attribute__((ext_vector_type(8)));
typedef float    f16v __attribute__((ext_vector_type(16)));

#define G1 0.13533528f        // exp(-2)
#define G2 3.3546263e-4f      // exp(-8)
#define G3 1.5229979e-8f      // exp(-18)

// 7-bin window at rows i0..i0+6 via factored Gaussian (2 exp + 1 rcp):
//   w(t) = W0 * R^t * G(t), W0=exp(-968 v^2), R=exp(88 v), v = x - c_mid
__device__ __forceinline__ float window7(float x, int& i0, float* w)
{
    x = fminf(fmaxf(x, 0.0f), 1.0f);
    int ka = (int)floorf(fmaf(x, 22.0f, 0.5f));
    i0 = min(max(ka - 3, 0), 16);
    float v  = fmaf((float)(i0 + 3), -(1.0f / 22.0f), x);
    float W0 = __expf(-968.0f * v * v);
    float R  = __expf(88.0f * v);
    float Ri = __builtin_amdgcn_rcpf(R);
    float R2 = R * R,   R3 = R2 * R;
    float R2i = Ri * Ri, R3i = R2i * Ri;
    w[0] = W0 * (R3i * G3);
    w[1] = W0 * (R2i * G2);
    w[2] = W0 * (Ri  * G1);
    w[3] = W0;
    w[4] = W0 * (R   * G1);
    w[5] = W0 * (R2  * G2);
    w[6] = W0 * (R3  * G3);
    return ((w[0] + w[6]) + (w[1] + w[5])) + ((w[2] + w[4]) + w[3]);
}

// ---------------- K1: fused Parzen-window + MFMA joint histogram ----------------
__global__ __launch_bounds__(256, 6)      // 6 waves/EU -> 6 blocks/CU
void mi_mfma(const float* __restrict__ pred,
             const float* __restrict__ targ,
             float* __restrict__ partial)      // [NBATCH*PBLK][NCELLS]
{
    __shared__ __align__(16) char smem[4 * WREG];   // 26496 B -> 6 blocks/CU

    const int p    = blockIdx.x;
    const int b    = blockIdx.y;
    const int wv   = threadIdx.x >> 6;
    const int lane = threadIdx.x & 63;
    const int m    = lane & 31;               // tile row for fragment reads
    const int h    = lane >> 5;               // k-half selector
    const int mr   = m < NBINS ? m : NBINS - 1;  // clamped read row (m>=23
                                              // feeds C rows/cols discarded)

    char* wbase = smem + wv * WREG;
    _Float16* Aimg = (_Float16*)wbase;
    _Float16* Bimg = (_Float16*)(wbase + IMGB);
    const _Float16* Ard = Aimg + mr * RS + 8 * h;
    const _Float16* Brd = Bimg + mr * RS + 8 * h;

    const float* __restrict__ px =
        pred + (size_t)b * NVOX + (size_t)p * VPB + (size_t)wv * VPW;
    const float* __restrict__ py =
        targ + (size_t)b * NVOX + (size_t)p * VPB + (size_t)wv * VPW;

    f16v acc = {};

    for (int c = 0; c < NCHUNK; ++c) {
        // zero both images' 23 rows: one contiguous 6624 B span
        vf4 z = {0.f, 0.f, 0.f, 0.f};
        #pragma unroll
        for (int it = 0; it < 6; ++it)
            *(vf4*)(wbase + (it * 64 + lane) * 16) = z;
        if (lane < 30)
            *(vf4*)(wbase + (384 + lane) * 16) = z;

        float x = __builtin_nontemporal_load(px + c * 64 + lane);
        float y = __builtin_nontemporal_load(py + c * 64 + lane);

        int ia, ja;
        float wa[7], wb[7];
        float sa = window7(x, ia, wa);
        float sb = window7(y, ja, wb);
        float inv = __builtin_amdgcn_rcpf(sa * sb);   // fold both norms onto A

        #pragma unroll
        for (int t = 0; t < 7; ++t) {
            Aimg[(ia + t) * RS + lane] = (_Float16)(wa[t] * inv);  // RNE cvt
            Bimg[(ja + t) * RS + lane] = (_Float16)wb[t];
        }

        // 4 k-steps of 32x32x16; reads bank-balanced (bank base 4m+4h+8s)
        #pragma unroll
        for (int s = 0; s < 4; ++s) {
            h8 Af = *(const h8*)(Ard + 16 * s);
            h8 Bf = *(const h8*)(Brd + 16 * s);
            acc = __builtin_amdgcn_mfma_f32_32x32x16_f16(Af, Bf, acc, 0, 0, 0);
        }
    }

    // epilogue: C layout col=lane&31, row=(reg&3)+8*(reg>>2)+4*h (m74/m101)
    float* tile = (float*)wbase;               // reuse wave region (4224 B)
    #pragma unroll
    for (int r = 0; r < 16; ++r) {
        int row = (r & 3) + 8 * (r >> 2) + 4 * h;
        tile[row * 33 + m] = acc[r];
    }
    __syncthreads();
    for (int c = threadIdx.x; c < NCELLS; c += 256) {
        int i = c / NBINS, j = c % NBINS;
        float s = 0.0f;
        #pragma unroll
        for (int w = 0; w < 4; ++w)
            s += ((const float*)(smem + w * WREG))[i * 33 + j];
        partial[((size_t)(b * PBLK + p)) * NCELLS + c] = s;   // coalesced rows
    }
}

// ------ K2: coalesced + parallel fp64 reduction (24 blocks per batch) ------
__global__ __launch_bounds__(256)
void mi_reduce(const float* __restrict__ partial, double* __restrict__ pab64)
{
    const int g = blockIdx.x;                 // 0..RBLK-1
    const int b = blockIdx.y;
    const int t = threadIdx.x;
    const float* __restrict__ src =
        partial + ((size_t)b * PBLK + (size_t)g * RPB) * NCELLS;

    double a0 = 0.0, a1 = 0.0, a2 = 0.0;
    #pragma unroll
    for (int p = 0; p < RPB; ++p) {
        const float* __restrict__ row = src + (size_t)p * NCELLS;
        a0 += (double)row[t];
        a1 += (double)row[256 + t];
        if (t < NCELLS - 512) a2 += (double)row[512 + t];
    }
    atomicAdd(&pab64[b * NCELLS + t],       a0);
    atomicAdd(&pab64[b * NCELLS + 256 + t], a1);
    if (t < NCELLS - 512) atomicAdd(&pab64[b * NCELLS + 512 + t], a2);
}

// ---------------- K3: fp64 marginals + MI ----------------
__global__ __launch_bounds__(256)
void mi_final(const double* __restrict__ pab64, float* __restrict__ out)
{
    __shared__ double s_pab[NCELLS];
    __shared__ double s_pa[NBINS];
    __shared__ double s_pb[NBINS];
    __shared__ double s_red[4];

    double total = 0.0;
    for (int b = 0; b < NBATCH; ++b) {
        for (int c = threadIdx.x; c < NCELLS; c += 256)
            s_pab[c] = pab64[b * NCELLS + c] * (1.0 / (double)NVOX);
        __syncthreads();
        if (threadIdx.x < NBINS) {
            const int i = threadIdx.x;
            double r = 0.0, cl = 0.0;
            for (int j = 0; j < NBINS; ++j) {
                r  += s_pab[i * NBINS + j];
                cl += s_pab[j * NBINS + i];
            }
            s_pa[i] = r; s_pb[i] = cl;
        }
        __syncthreads();
        double t = 0.0;
        for (int c = threadIdx.x; c < NCELLS; c += 256) {
            double pv   = s_pab[c];
            double papb = s_pa[c / NBINS] * s_pb[c % NBINS];
            t += pv * log((pv + 1e-7) / (papb + 1e-7) + 1e-7);
        }
        #pragma unroll
        for (int off = 32; off > 0; off >>= 1) t += __shfl_down(t, off, 64);
        if ((threadIdx.x & 63) == 0) s_red[threadIdx.x >> 6] = t;
        __syncthreads();
        if (threadIdx.x == 0) total += s_red[0] + s_red[1] + s_red[2] + s_red[3];
        __syncthreads();
    }
    if (threadIdx.x == 0) out[0] = (float)(-total * 0.25);
}

extern "C" void kernel_launch(void* const* d_in, const int* in_sizes, int n_in,
                              void* d_out, int out_size, void* d_ws, size_t ws_size,
                              hipStream_t stream)
{
    const float* pred = (const float*)d_in[0];
    const float* targ = (const float*)d_in[1];
    float* out = (float*)d_out;
    char* ws = (char*)d_ws;

    // layout: [partial: NBATCH*PBLK*NCELLS f32 = 3.25 MB][pab64: 2116 f64]
    const size_t off_partial = 0;
    const size_t off_pab64   =
        ((size_t)NBATCH * PBLK * NCELLS * 4 + 255) & ~(size_t)255;

    float*  partial = (float*)(ws + off_partial);
    double* pab64   = (double*)(ws + off_pab64);

    (void)hipMemsetAsync(pab64, 0, (size_t)NBATCH * NCELLS * sizeof(double), stream);
    mi_mfma  <<<dim3(PBLK, NBATCH), 256, 0, stream>>>(pred, targ, partial);
    mi_reduce<<<dim3(RBLK, NBATCH), 256, 0, stream>>>(partial, pab64);
    mi_final <<<1, 256, 0, stream>>>(pab64, out);
}

// Round 12
// 110.007 us; speedup vs baseline: 1.1032x; 1.0152x over previous
//
#include <hip/hip_runtime.h>
#include <math.h>

// MutualInformationLoss on MI355X — round 12.
// r11 regression root-cause: per-chunk scalar loads INSIDE the chunk loop
// exposed ~900-cyc HBM latency per chunk (load->use, loop-carried). r12
// restores r8/r10-style upfront register preload (2x vf4 + 1x dword per lane,
// any voxel->k permutation is valid since A/B share it), keeping r11's
// 23-row images / 6 blocks/CU / single-residency 1536-block grid.
// Tail = measured-best r8 structure: 17 KB memset + reduce(24x4) + final(1).

#define NBINS   23
#define NCELLS  529
#define NBATCH  4
#define NVOX    884736
#define PBLK    384               // blocks per batch: 384 * 2304 = 884736
#define VPB     2304              // voxels per block
#define VPW     576               // voxels per wave (9 chunks of 64)
#define NCHUNK  9
#define RPB     16                // partial rows per reduce block
#define RBLK    (PBLK / RPB)      // 24
#define RS      72                // image row stride in halves (144 B)
#define IMGB    (23 * RS * 2)     // 3312 B per image (23 rows, 16B-multiple)
#define WREG    (2 * IMGB)        // 6624 B per wave (A + B images)

typedef float    vf4  __attribute__((ext_vector_type(4)));
typedef _Float16 h8   __attribute__((ext_vector_type(8)));
typedef float    f16v __attribute__((ext_vector_type(16)));

#define G1 0.13533528f        // exp(-2)
#define G2 3.3546263e-4f      // exp(-8)
#define G3 1.5229979e-8f      // exp(-18)

// 7-bin window at rows i0..i0+6 via factored Gaussian (2 exp + 1 rcp):
//   w(t) = W0 * R^t * G(t), W0=exp(-968 v^2), R=exp(88 v), v = x - c_mid
__device__ __forceinline__ float window7(float x, int& i0, float* w)
{
    x = fminf(fmaxf(x, 0.0f), 1.0f);
    int ka = (int)floorf(fmaf(x, 22.0f, 0.5f));
    i0 = min(max(ka - 3, 0), 16);
    float v  = fmaf((float)(i0 + 3), -(1.0f / 22.0f), x);
    float W0 = __expf(-968.0f * v * v);
    float R  = __expf(88.0f * v);
    float Ri = __builtin_amdgcn_rcpf(R);
    float R2 = R * R,   R3 = R2 * R;
    float R2i = Ri * Ri, R3i = R2i * Ri;
    w[0] = W0 * (R3i * G3);
    w[1] = W0 * (R2i * G2);
    w[2] = W0 * (Ri  * G1);
    w[3] = W0;
    w[4] = W0 * (R   * G1);
    w[5] = W0 * (R2  * G2);
    w[6] = W0 * (R3  * G3);
    return ((w[0] + w[6]) + (w[1] + w[5])) + ((w[2] + w[4]) + w[3]);
}

// ---------------- K1: fused Parzen-window + MFMA joint histogram ----------------
__global__ __launch_bounds__(256, 6)      // 6 blocks/CU (LDS 26.5 KB)
void mi_mfma(const float* __restrict__ pred,
             const float* __restrict__ targ,
             float* __restrict__ partial)      // [NBATCH*PBLK][NCELLS]
{
    __shared__ __align__(16) char smem[4 * WREG];   // 26496 B

    const int p    = blockIdx.x;
    const int b    = blockIdx.y;
    const int wv   = threadIdx.x >> 6;
    const int lane = threadIdx.x & 63;
    const int m    = lane & 31;               // tile row for fragment reads
    const int h    = lane >> 5;               // k-half selector
    const int mr   = m < NBINS ? m : NBINS - 1;  // clamped read row (m>=23
                                              // feeds C rows/cols discarded)

    char* wbase = smem + wv * WREG;
    _Float16* Aimg = (_Float16*)wbase;
    _Float16* Bimg = (_Float16*)(wbase + IMGB);
    const _Float16* Ard = Aimg + mr * RS + 8 * h;
    const _Float16* Brd = Bimg + mr * RS + 8 * h;

    const float* __restrict__ px =
        pred + (size_t)b * NVOX + (size_t)p * VPB + (size_t)wv * VPW;
    const float* __restrict__ py =
        targ + (size_t)b * NVOX + (size_t)p * VPB + (size_t)wv * VPW;

    // upfront preload: 9 voxels/lane (chunk c uses element c; the voxel->k
    // permutation is shared by A and B, so the inner product is unchanged)
    vf4 X1 = *(const vf4*)(px + 4 * lane);
    vf4 X2 = *(const vf4*)(px + 256 + 4 * lane);
    float x8 = px[512 + lane];
    vf4 Y1 = *(const vf4*)(py + 4 * lane);
    vf4 Y2 = *(const vf4*)(py + 256 + 4 * lane);
    float y8 = py[512 + lane];
    float xs[NCHUNK] = {X1.x, X1.y, X1.z, X1.w, X2.x, X2.y, X2.z, X2.w, x8};
    float ys[NCHUNK] = {Y1.x, Y1.y, Y1.z, Y1.w, Y2.x, Y2.y, Y2.z, Y2.w, y8};

    f16v acc = {};

    #pragma unroll
    for (int c = 0; c < NCHUNK; ++c) {
        // zero both images' 23 rows: one contiguous 6624 B span
        vf4 z = {0.f, 0.f, 0.f, 0.f};
        #pragma unroll
        for (int it = 0; it < 6; ++it)
            *(vf4*)(wbase + (it * 64 + lane) * 16) = z;
        if (lane < 30)
            *(vf4*)(wbase + (384 + lane) * 16) = z;

        int ia, ja;
        float wa[7], wb[7];
        float sa = window7(xs[c], ia, wa);
        float sb = window7(ys[c], ja, wb);
        float inv = __builtin_amdgcn_rcpf(sa * sb);   // fold both norms onto A

        #pragma unroll
        for (int t = 0; t < 7; ++t) {
            Aimg[(ia + t) * RS + lane] = (_Float16)(wa[t] * inv);  // RNE cvt
            Bimg[(ja + t) * RS + lane] = (_Float16)wb[t];
        }

        // 4 k-steps of 32x32x16; reads bank-balanced (bank base 4m+4h+8s)
        #pragma unroll
        for (int s = 0; s < 4; ++s) {
            h8 Af = *(const h8*)(Ard + 16 * s);
            h8 Bf = *(const h8*)(Brd + 16 * s);
            acc = __builtin_amdgcn_mfma_f32_32x32x16_f16(Af, Bf, acc, 0, 0, 0);
        }
    }

    // epilogue: C layout col=lane&31, row=(reg&3)+8*(reg>>2)+4*h (m74/m101)
    float* tile = (float*)wbase;               // reuse wave region (4224 B)
    #pragma unroll
    for (int r = 0; r < 16; ++r) {
        int row = (r & 3) + 8 * (r >> 2) + 4 * h;
        tile[row * 33 + m] = acc[r];
    }
    __syncthreads();
    for (int c = threadIdx.x; c < NCELLS; c += 256) {
        int i = c / NBINS, j = c % NBINS;
        float s = 0.0f;
        #pragma unroll
        for (int w = 0; w < 4; ++w)
            s += ((const float*)(smem + w * WREG))[i * 33 + j];
        partial[((size_t)(b * PBLK + p)) * NCELLS + c] = s;   // coalesced rows
    }
}

// ------ K2: coalesced + parallel fp64 reduction (24 blocks per batch) ------
__global__ __launch_bounds__(256)
void mi_reduce(const float* __restrict__ partial, double* __restrict__ pab64)
{
    const int g = blockIdx.x;                 // 0..RBLK-1
    const int b = blockIdx.y;
    const int t = threadIdx.x;
    const float* __restrict__ src =
        partial + ((size_t)b * PBLK + (size_t)g * RPB) * NCELLS;

    double a0 = 0.0, a1 = 0.0, a2 = 0.0;
    #pragma unroll
    for (int p = 0; p < RPB; ++p) {
        const float* __restrict__ row = src + (size_t)p * NCELLS;
        a0 += (double)row[t];
        a1 += (double)row[256 + t];
        if (t < NCELLS - 512) a2 += (double)row[512 + t];
    }
    atomicAdd(&pab64[b * NCELLS + t],       a0);
    atomicAdd(&pab64[b * NCELLS + 256 + t], a1);
    if (t < NCELLS - 512) atomicAdd(&pab64[b * NCELLS + 512 + t], a2);
}

// ---------------- K3: fp64 marginals + MI ----------------
__global__ __launch_bounds__(256)
void mi_final(const double* __restrict__ pab64, float* __restrict__ out)
{
    __shared__ double s_pab[NCELLS];
    __shared__ double s_pa[NBINS];
    __shared__ double s_pb[NBINS];
    __shared__ double s_red[4];

    double total = 0.0;
    for (int b = 0; b < NBATCH; ++b) {
        for (int c = threadIdx.x; c < NCELLS; c += 256)
            s_pab[c] = pab64[b * NCELLS + c] * (1.0 / (double)NVOX);
        __syncthreads();
        if (threadIdx.x < NBINS) {
            const int i = threadIdx.x;
            double r = 0.0, cl = 0.0;
            for (int j = 0; j < NBINS; ++j) {
                r  += s_pab[i * NBINS + j];
                cl += s_pab[j * NBINS + i];
            }
            s_pa[i] = r; s_pb[i] = cl;
        }
        __syncthreads();
        double t = 0.0;
        for (int c = threadIdx.x; c < NCELLS; c += 256) {
            double pv   = s_pab[c];
            double papb = s_pa[c / NBINS] * s_pb[c % NBINS];
            t += pv * log((pv + 1e-7) / (papb + 1e-7) + 1e-7);
        }
        #pragma unroll
        for (int off = 32; off > 0; off >>= 1) t += __shfl_down(t, off, 64);
        if ((threadIdx.x & 63) == 0) s_red[threadIdx.x >> 6] = t;
        __syncthreads();
        if (threadIdx.x == 0) total += s_red[0] + s_red[1] + s_red[2] + s_red[3];
        __syncthreads();
    }
    if (threadIdx.x == 0) out[0] = (float)(-total * 0.25);
}

extern "C" void kernel_launch(void* const* d_in, const int* in_sizes, int n_in,
                              void* d_out, int out_size, void* d_ws, size_t ws_size,
                              hipStream_t stream)
{
    const float* pred = (const float*)d_in[0];
    const float* targ = (const float*)d_in[1];
    float* out = (float*)d_out;
    char* ws = (char*)d_ws;

    // layout: [partial: NBATCH*PBLK*NCELLS f32 = 3.25 MB][pab64: 2116 f64]
    const size_t off_partial = 0;
    const size_t off_pab64   =
        ((size_t)NBATCH * PBLK * NCELLS * 4 + 255) & ~(size_t)255;

    float*  partial = (float*)(ws + off_partial);
    double* pab64   = (double*)(ws + off_pab64);

    (void)hipMemsetAsync(pab64, 0, (size_t)NBATCH * NCELLS * sizeof(double), stream);
    mi_mfma  <<<dim3(PBLK, NBATCH), 256, 0, stream>>>(pred, targ, partial);
    mi_reduce<<<dim3(RBLK, NBATCH), 256, 0, stream>>>(partial, pab64);
    mi_final <<<1, 256, 0, stream>>>(pab64, out);
}